// Round 5
// baseline (3330.963 us; speedup 1.0000x reference)
//
#include <hip/hip_runtime.h>

// SpikeTimeSeriesForecaster: 3-layer LIF SNN, T=50, rate decode over last 10.
// Bit-exact fp32 (proven: absmax 0.0 rounds 3-4). Round 5: occupancy.
//  - BB=8 rows/block -> 1024 blocks -> 4 blocks/CU -> 32 waves/CU (100% occ).
//  - Spikes expanded once by producer into fp32 {0,1} LDS arrays; consumers
//    use broadcast ds_read (wave-uniform address, conflict-free).
//  - s@W via v_pk_fma_f32; k-chain strictly ascending per accumulator ->
//    bit-identical to numpy fp32 sgemm + separately-rounded LIF update.

typedef float f32x2 __attribute__((ext_vector_type(2)));
typedef float f32x4 __attribute__((ext_vector_type(4)));

#define B_TOT  8192
#define IN     256
#define H1     512
#define H2     256
#define NOUT   64
#define T_STEPS 50
#define WIN    10
#define BB     8
#define NTHR   512

// acc = a*b + acc, packed 2x fp32, IEEE rn per half (bit-exact to 2 scalar fmas)
__device__ __forceinline__ void pk_fma(f32x2& acc, f32x2 a, f32x2 b) {
    asm("v_pk_fma_f32 %0, %1, %2, %0" : "+v"(acc) : "v"(a), "v"(b));
}

// numpy LIF membrane update: rn(0.9f*V) then rn(t+I); no FMA contraction.
__device__ __forceinline__ float lif_v(float V, float I) {
    return __fadd_rn(__fmul_rn(0.9f, V), I);
}

__global__ __launch_bounds__(NTHR, 8)
void snn_lif_fp32_occ(const float* __restrict__ x,
                      const float* __restrict__ W1, const float* __restrict__ b1,
                      const float* __restrict__ W2, const float* __restrict__ b2,
                      const float* __restrict__ W3, const float* __restrict__ b3,
                      float* __restrict__ out)
{
    // S1f: layer-1 spike floats [h1][b] (16 KiB); aliased as xs[BB][IN] in phase 0.
    __shared__ __align__(16) float S1f[H1 * BB];
    // S2f: layer-2 spike floats [h2][b] (8 KiB).
    __shared__ __align__(16) float S2f[H2 * BB];

    const int t  = threadIdx.x;            // 0..511
    const int b0 = blockIdx.x * BB;

    // ---- phase 0: stage x, compute I1[b][h1=t] via k-ascending fma chain ----
    float* xs = S1f;                       // [BB][IN] = 8 KiB, dead after phase 0
    for (int i = t; i < BB * IN; i += NTHR) xs[i] = x[(size_t)b0 * IN + i];
    __syncthreads();

    float I1r[BB];
    #pragma unroll
    for (int b = 0; b < BB; b++) I1r[b] = 0.0f;
    for (int k = 0; k < IN; k++) {
        float w = W1[k * H1 + t];          // coalesced; xs reads are broadcast
        #pragma unroll
        for (int b = 0; b < BB; b++)
            I1r[b] = __fmaf_rn(xs[b * IN + k], w, I1r[b]);   // sgemm FMA order
    }
    {
        float bb = b1[t];
        #pragma unroll
        for (int b = 0; b < BB; b++) I1r[b] = __fadd_rn(I1r[b], bb);
    }
    __syncthreads();                       // xs dead; S1f becomes the spike array

    // ---- per-thread state ----
    float V1[BB];                          // layer 1: h1 = t owns all 8 rows
    #pragma unroll
    for (int b = 0; b < BB; b++) V1[b] = 0.0f;
    unsigned r1 = 0;

    const int jj = t & (H2 - 1);           // layer-2 column
    const int g  = t >> 8;                 // 0/1: rows g*4 .. g*4+3 (wave-uniform)
    f32x2 accA, accB;                      // 4 accumulators as 2 pairs
    float V2[4];
    #pragma unroll
    for (int i = 0; i < 4; i++) V2[i] = 0.0f;
    unsigned r2 = 0;
    const float b2v = b2[jj];
    const float* w2c = W2 + jj;

    const int o    = t & (NOUT - 1);       // layer-3 column
    const int brow = t >> 6;               // 0..7: exactly one row (wave-uniform)
    float V3 = 0.0f;
    unsigned r3 = 0;
    int cnt = 0;
    const float b3v = b3[o];
    const float* w3c = W3 + o;

    // ---- time loop: 2 barriers per step ----
    for (int step = 0; step < T_STEPS; step++) {
        // layer 1: update 8 rows, expand spikes to floats, write S1f[t][0..7]
        float sf[BB];
        unsigned nr1 = 0;
        #pragma unroll
        for (int b = 0; b < BB; b++) {
            float V = lif_v(V1[b], I1r[b]);
            bool act = (V >= 1.0f) & !((r1 >> b) & 1u);
            V1[b] = act ? 0.0f : V;
            sf[b] = act ? 1.0f : 0.0f;
            nr1 |= (unsigned)act << b;
        }
        r1 = nr1;
        {
            f32x4* dst = (f32x4*)(S1f + t * BB);
            dst[0] = (f32x4){sf[0], sf[1], sf[2], sf[3]};
            dst[1] = (f32x4){sf[4], sf[5], sf[6], sf[7]};
        }
        __syncthreads();   // (A) S1f ready; also fences prev-step S2f readers

        // layer 2: 4 accs (rows g*4..g*4+3) x column jj.
        // per k: 1 coalesced w load + 1 broadcast ds_read_b128 + 2 v_pk_fma_f32
        accA = (f32x2){0.0f, 0.0f};
        accB = (f32x2){0.0f, 0.0f};
        const float* srow = S1f + g * 4;
        #pragma unroll 4
        for (int k = 0; k < H1; k++) {
            float w = w2c[(size_t)k * H2];
            f32x2 ws = {w, w};
            f32x4 s = *(const f32x4*)(srow + k * BB);
            pk_fma(accA, ws, __builtin_shufflevector(s, s, 0, 1));
            pk_fma(accB, ws, __builtin_shufflevector(s, s, 2, 3));
        }
        float sf2[4];
        unsigned nr2 = 0;
        #pragma unroll
        for (int i = 0; i < 4; i++) {
            float ai = (i < 2) ? accA[i & 1] : accB[i & 1];
            float I2 = __fadd_rn(ai, b2v);            // bias last, like numpy
            float V = lif_v(V2[i], I2);
            bool act = (V >= 1.0f) & !((r2 >> i) & 1u);
            V2[i] = act ? 0.0f : V;
            sf2[i] = act ? 1.0f : 0.0f;
            nr2 |= (unsigned)act << i;
        }
        r2 = nr2;
        {
            f32x4* dst = (f32x4*)(S2f + jj * BB + g * 4);
            dst[0] = (f32x4){sf2[0], sf2[1], sf2[2], sf2[3]};
        }
        __syncthreads();   // (B) S2f ready; also fences this-step S1f readers

        // layer 3: 1 acc (row brow) x column o.
        // per k: 1 coalesced w load + 1 broadcast ds_read_b32 + 1 v_fma
        float a3 = 0.0f;
        const float* s2r = S2f + brow;
        #pragma unroll 4
        for (int k = 0; k < H2; k++)
            a3 = __fmaf_rn(w3c[(size_t)k * NOUT], s2r[k * BB], a3);
        {
            float I3 = __fadd_rn(a3, b3v);
            float V = lif_v(V3, I3);
            bool act = (V >= 1.0f) & !(r3 & 1u);
            V3 = act ? 0.0f : V;
            r3 = (unsigned)act;
            if (step >= T_STEPS - WIN) cnt += (int)act;
        }
        // next-step S1f writes fenced by (B); next-step S2f writes by next (A)
    }

    // ---- output: mean over last WIN steps (fp32 division, like np) ----
    out[(size_t)(b0 + brow) * NOUT + o] = (float)cnt / 10.0f;
}

extern "C" void kernel_launch(void* const* d_in, const int* in_sizes, int n_in,
                              void* d_out, int out_size, void* d_ws, size_t ws_size,
                              hipStream_t stream)
{
    const float* x  = (const float*)d_in[0];
    const float* W1 = (const float*)d_in[1];
    const float* b1 = (const float*)d_in[2];
    const float* W2 = (const float*)d_in[3];
    const float* b2 = (const float*)d_in[4];
    const float* W3 = (const float*)d_in[5];
    const float* b3 = (const float*)d_in[6];
    float* out = (float*)d_out;

    dim3 grid(B_TOT / BB);   // 1024 blocks -> 4 blocks/CU
    dim3 block(NTHR);        // 512 threads = 8 waves
    hipLaunchKernelGGL(snn_lif_fp32_occ, grid, block, 0, stream,
                       x, W1, b1, W2, b2, W3, b3, out);
}